// Round 5
// baseline (678.076 us; speedup 1.0000x reference)
//
#include <hip/hip_runtime.h>

typedef __bf16 bf16;
typedef __bf16 bf16x4 __attribute__((ext_vector_type(4)));
typedef __bf16 bf16x8 __attribute__((ext_vector_type(8)));
typedef float  f32x4  __attribute__((ext_vector_type(4)));

#define BM 128
#define BN 128
#define BK 64

__device__ __forceinline__ void async_copy16(const void* g, void* l) {
    __builtin_amdgcn_global_load_lds(
        (__attribute__((address_space(1))) void*)(g),
        (__attribute__((address_space(3))) void*)(l),
        16, 0, 0);
}

// C[z,m,n] = alpha * rs[z,m] * sum_k A[z,m,k]*B[z,n,k]  (+bias[n])
// NT GEMM, z-batched, BK=64. 128^2 2-phase structure with:
//  - T1 band swizzle GATED to dense grids only (r4 post-mortem: with gx%8==0,
//    XCD = bx%8, so band remap gives XCD0 the always-live low-n0 causal
//    columns -> 12:1 live-block imbalance, S-GEMM 154->169us. Identity keeps
//    the live prefix spread evenly across XCDs).
//  - T3 minimum-2-phase prefetch: LDS double-buffer, stage(t+1) issued BEFORE
//    waiting tile t, wait vmcnt(8) (t's own 8 loads; t+1's stay in flight).
//    Per-thread ledger: exactly 8 loads/tile in issue order, so vmcnt(8)
//    retires through tile t. Closing barrier of iter t orders all reads of
//    buf p before iter t+1 stages into it (WAR safe). 2 barriers/tile.
// LDS rows are 128 B; 16B-group index XORed with row&7 both at stage and
// read time -> uniform 2-way bank access per quarter-wave (free, m136).
// qkv_mode: N spans 3 concatenated 1024-col output buffers C0/C1/C2.
// rev_m: longest-work-first block order for triangular (causal/kcap) grids.
__global__ __launch_bounds__(256)
void gemm_nt(const bf16* __restrict__ A, int lda, size_t az,
             const bf16* __restrict__ B, int ldb, size_t bz,
             void* __restrict__ C0, void* __restrict__ C1, void* __restrict__ C2,
             int ldc, size_t cz,
             int M, int N, int K, float alpha,
             const float* __restrict__ bias,
             const float* __restrict__ row_scale, int rsz,
             int out_bf16, int qkv_mode, int causal_skip, int kcap,
             int row_off, int rev_m)
{
    int z  = blockIdx.z;
    int by = rev_m ? (gridDim.y - 1 - blockIdx.y) : blockIdx.y;
    int m0 = by * BM;
    int gx = (int)gridDim.x;
    int bx = (int)blockIdx.x;
    // T1 band swizzle: dense grids only (causal balance, see header comment)
    if ((gx & 7) == 0 && !causal_skip) bx = ((bx & 7) * (gx >> 3)) + (bx >> 3);
    int n0 = bx * BN;
    if (causal_skip && n0 > row_off + m0 + BM - 1) return;  // above diagonal
    int Keff = kcap ? min(K, row_off + m0 + BM) : K;        // multiple of 128
    int nk = Keff / BK;
    A += (size_t)z * az;
    B += (size_t)z * bz;

    __shared__ __attribute__((aligned(16))) bf16 As[2][BM * BK];  // 2 x 16 KB
    __shared__ __attribute__((aligned(16))) bf16 Bs[2][BN * BK];  // 2 x 16 KB

    int tid  = threadIdx.x;
    int lane = tid & 63;
    int q    = lane >> 4;    // 0..3  (k-subgroup)
    int r    = lane & 15;    // 0..15 (row-in-16)
    int wave = tid >> 6;
    int wm   = (wave >> 1) * 64;
    int wn   = (wave & 1) * 64;
    int sw   = r & 7;                                     // read-side swizzle
    int gsw  = (((tid & 7) ^ ((tid >> 3) & 7)) * 8);      // stage-side swizzle

    f32x4 acc[4][4];
#pragma unroll
    for (int i = 0; i < 4; i++)
#pragma unroll
        for (int j = 0; j < 4; j++) acc[i][j] = (f32x4){0.f, 0.f, 0.f, 0.f};

    // staging: 8 issues x 4 KB = 32 KB per k-tile. Thread tid owns LDS bytes
    // tid*16 (+4 KB per issue); fetches swizzled global k-group so LDS group
    // p of row rr holds global group p^(rr&7).
    const bf16* Ag = A + (size_t)(m0 + (tid >> 3)) * lda + gsw;
    const bf16* Bg = B + (size_t)(n0 + (tid >> 3)) * ldb + gsw;
    size_t astep = (size_t)32 * lda;
    size_t bstep = (size_t)32 * ldb;

    auto stage = [&](int kt, int pb) {
        char* la = (char*)&As[pb][0] + tid * 16;
        char* lb = (char*)&Bs[pb][0] + tid * 16;
        const bf16* ga = Ag + (size_t)kt * BK;
        const bf16* gb = Bg + (size_t)kt * BK;
#pragma unroll
        for (int i = 0; i < 4; i++) {
            async_copy16(ga + i * astep, la + i * 4096);
            async_copy16(gb + i * bstep, lb + i * 4096);
        }
    };

    stage(0, 0);  // prologue

    for (int t = 0; t < nk; ++t) {
        int pb = t & 1;
        if (t + 1 < nk) {
            stage(t + 1, pb ^ 1);                              // prefetch next
            asm volatile("s_waitcnt vmcnt(8)" ::: "memory");   // tile t landed
        } else {
            asm volatile("s_waitcnt vmcnt(0)" ::: "memory");
        }
        __syncthreads();

#pragma unroll
        for (int kk = 0; kk < 2; kk++) {
            bf16x8 av[4], bv[4];
#pragma unroll
            for (int mi = 0; mi < 4; mi++)
                av[mi] = *(const bf16x8*)&As[pb][(wm + mi * 16 + r) * BK
                                               + (((kk << 2) + q) ^ sw) * 8];
#pragma unroll
            for (int ni = 0; ni < 4; ni++)
                bv[ni] = *(const bf16x8*)&Bs[pb][(wn + ni * 16 + r) * BK
                                               + (((kk << 2) + q) ^ sw) * 8];
#pragma unroll
            for (int mi = 0; mi < 4; mi++)
#pragma unroll
                for (int ni = 0; ni < 4; ni++)
                    acc[mi][ni] = __builtin_amdgcn_mfma_f32_16x16x32_bf16(
                        av[mi], bv[ni], acc[mi][ni], 0, 0, 0);
        }
        __syncthreads();  // all reads of buf pb done before iter t+1 stages it
    }

    const float* rs = row_scale ? row_scale + (size_t)z * rsz : nullptr;
    void* Cb = C0;
    if (qkv_mode) { int sel = n0 >> 10; Cb = sel == 0 ? C0 : (sel == 1 ? C1 : C2); }
    // epilogue: C/D layout col=lane&15, row=(lane>>4)*4+j  (m89-verified)
#pragma unroll
    for (int mi = 0; mi < 4; mi++) {
#pragma unroll
        for (int ni = 0; ni < 4; ni++) {
#pragma unroll
            for (int j = 0; j < 4; j++) {
                int row = m0 + wm + mi * 16 + q * 4 + j;
                int col = n0 + wn + ni * 16 + r;
                if (qkv_mode) col &= 1023;
                float v = acc[mi][ni][j] * alpha;
                if (rs)   v *= rs[row];
                if (bias) v += bias[col];
                if (out_bf16) ((bf16*)Cb + (size_t)z * cz)[(size_t)row * ldc + col] = (bf16)v;
                else          ((float*)Cb + (size_t)z * cz)[(size_t)row * ldc + col] = v;
            }
        }
    }
}

// One block per score row, bf16 scores in/out IN PLACE (row stride T bf16).
// Writes unnormalized P (zero-padded to the 128-block boundary) + 1/rowsum.
__global__ __launch_bounds__(256)
void softmax_causal(bf16* __restrict__ S, float* __restrict__ inv_l,
                    int T, int toff, int chunk)
{
    int tr = blockIdx.x, z = blockIdx.y;
    int t  = toff + tr;
    int L  = t + 1;
    int Lw = ((t >> 7) + 1) << 7;
    bf16* row = S + ((size_t)z * chunk + tr) * T;
    int tid = threadIdx.x;
    __shared__ float buf[4096];
    __shared__ float red[4];

    for (int s = tid * 8; s < Lw; s += 2048) {
        bf16x8 v = *(const bf16x8*)(row + s);
#pragma unroll
        for (int i = 0; i < 8; i++)
            buf[s + i] = (s + i < L) ? (float)v[i] : -3.0e38f;
    }
    __syncthreads();

    float m = -3.0e38f;
    for (int s = tid; s < Lw; s += 256) m = fmaxf(m, buf[s]);
#pragma unroll
    for (int off = 32; off > 0; off >>= 1) m = fmaxf(m, __shfl_down(m, off, 64));
    if ((tid & 63) == 0) red[tid >> 6] = m;
    __syncthreads();
    m = fmaxf(fmaxf(red[0], red[1]), fmaxf(red[2], red[3]));
    __syncthreads();

    float sum = 0.f;
    for (int s = tid * 8; s < Lw; s += 2048) {
        bf16x8 o;
#pragma unroll
        for (int i = 0; i < 8; i++) {
            float e = __expf(buf[s + i] - m);  // padded lanes -> 0
            sum += e;
            o[i] = (bf16)e;
        }
        *(bf16x8*)(row + s) = o;
    }
#pragma unroll
    for (int off = 32; off > 0; off >>= 1) sum += __shfl_down(sum, off, 64);
    if ((tid & 63) == 0) red[tid >> 6] = sum;
    __syncthreads();
    if (tid == 0) inv_l[(size_t)z * chunk + tr] = 1.0f / (red[0] + red[1] + red[2] + red[3]);
}

// batched transpose: V (B,T,C) -> VT (B,C,T), bf16
__global__ __launch_bounds__(256)
void transpose64(const bf16* __restrict__ V, bf16* __restrict__ VT, int T, int C)
{
    __shared__ bf16 tile[64][65];
    int b  = blockIdx.z;
    int s0 = blockIdx.x * 64, d0 = blockIdx.y * 64;
    const bf16* Vb  = V  + (size_t)b * T * C;
    bf16*       VTb = VT + (size_t)b * T * C;
    int tx = threadIdx.x & 63, ty = threadIdx.x >> 6;
#pragma unroll
    for (int i = 0; i < 64; i += 4)
        tile[ty + i][tx] = Vb[(size_t)(s0 + ty + i) * C + d0 + tx];
    __syncthreads();
#pragma unroll
    for (int i = 0; i < 64; i += 4)
        VTb[(size_t)(d0 + ty + i) * T + s0 + tx] = tile[tx][ty + i];
}

__global__ void cvt_f32_bf16(const float4* __restrict__ in, bf16x4* __restrict__ out, int n4)
{
    int i = blockIdx.x * blockDim.x + threadIdx.x;
    int stride = gridDim.x * blockDim.x;
    for (; i < n4; i += stride) {
        float4 v = in[i];
        bf16x4 o = { (bf16)v.x, (bf16)v.y, (bf16)v.z, (bf16)v.w };
        out[i] = o;
    }
}

extern "C" void kernel_launch(void* const* d_in, const int* in_sizes, int n_in,
                              void* d_out, int out_size, void* d_ws, size_t ws_size,
                              hipStream_t stream)
{
    const int B = 4, T = 4096, C = 1024, M = B * T;
    const float* x  = (const float*)d_in[0];
    const float* Wq = (const float*)d_in[1];
    const float* Wk = (const float*)d_in[2];
    const float* Wv = (const float*)d_in[3];
    const float* Wo = (const float*)d_in[4];
    const float* bo = (const float*)d_in[5];
    float* out = (float*)d_out;

    char* ws = (char*)d_ws;
    size_t off = 0;
    auto alloc = [&](size_t bytes) -> char* {
        char* p = ws + off;
        off += (bytes + 255) & ~(size_t)255;
        return p;
    };
    bf16* Wcat = (bf16*)alloc((size_t)3 * C * C * 2);  // [Wq; Wk; Wv]
    bf16* Wob  = (bf16*)alloc((size_t)C * C * 2);
    bf16* Qb   = (bf16*)alloc((size_t)M * C * 2);
    bf16* Kb   = (bf16*)alloc((size_t)M * C * 2);
    bf16* VT   = (bf16*)alloc((size_t)M * C * 2);

    // Preferred plan (chunk = T, ~232 MB — ws proven >= 235 MB in round 1):
    //   S region hosts xb and raw-V during projection (dead before S written);
    //   attention output O aliases Qb (Q dead after the single S-GEMM).
    size_t base = off;
    int chunk = T;
    bf16 *S, *xb, *Vtmp, *Ob;
    float* inv_l;
    {
        size_t need = base + (((size_t)B * T * T * 2 + 255) & ~(size_t)255)
                           + (((size_t)B * T * 4 + 255) & ~(size_t)255);
        if (need <= ws_size) {
            S     = (bf16*)alloc((size_t)B * T * T * 2);
            inv_l = (float*)alloc((size_t)B * T * 4);
            xb    = S;
            Vtmp  = S + (size_t)M * C;   // 32 MB past xb, inside S region
            Ob    = Qb;                  // O overwrites Q after S-GEMM
        } else {
            Ob = (bf16*)alloc((size_t)M * C * 2);
            chunk = T / 2;
            while (chunk > 1024) {
                size_t nd = off + (((size_t)B * chunk * T * 2 + 255) & ~(size_t)255)
                                + (((size_t)B * chunk * 4 + 255) & ~(size_t)255);
                if (nd <= ws_size) break;
                chunk >>= 1;
            }
            S     = (bf16*)alloc((size_t)B * chunk * T * 2);
            inv_l = (float*)alloc((size_t)B * chunk * 4);
            xb    = S;   // x dead after QKV projection
            Vtmp  = Ob;  // V staged in Ob, transposed before PV writes Ob
        }
    }

    dim3 blk(256);

    cvt_f32_bf16<<<dim3(4096), blk, 0, stream>>>((const float4*)x,  (bf16x4*)xb, M * C / 4);
    cvt_f32_bf16<<<dim3(1024), blk, 0, stream>>>((const float4*)Wq, (bf16x4*)(Wcat),             C * C / 4);
    cvt_f32_bf16<<<dim3(1024), blk, 0, stream>>>((const float4*)Wk, (bf16x4*)(Wcat + C * C),     C * C / 4);
    cvt_f32_bf16<<<dim3(1024), blk, 0, stream>>>((const float4*)Wv, (bf16x4*)(Wcat + 2 * C * C), C * C / 4);
    cvt_f32_bf16<<<dim3(1024), blk, 0, stream>>>((const float4*)Wo, (bf16x4*)Wob, C * C / 4);

    // fused QKV projection: [Q|K|V] = X * Wcat^T
    gemm_nt<<<dim3(3 * C / BN, M / BM, 1), blk, 0, stream>>>(
        xb, C, 0, Wcat, C, 0, Qb, Kb, Vtmp, C, 0, M, 3 * C, C, 1.f,
        nullptr, nullptr, 0, 1, 1, 0, 0, 0, 0);
    transpose64<<<dim3(T / 64, C / 64, B), blk, 0, stream>>>(Vtmp, VT, T, C);

    const float scale = 0.03125f;  // 1/sqrt(1024)
    for (int toff = 0; toff < T; toff += chunk) {
        // S = Q_chunk * K^T * scale  (bf16 out, causal skip, longest-m first)
        gemm_nt<<<dim3(T / BN, chunk / BM, B), blk, 0, stream>>>(
            Qb + (size_t)toff * C, C, (size_t)T * C,
            Kb, C, (size_t)T * C,
            S, nullptr, nullptr, T, (size_t)chunk * T,
            chunk, T, C, scale,
            nullptr, nullptr, 0, 1, 0, 1, 0, toff, 1);
        // causal softmax in place -> unnormalized bf16 P + 1/rowsum
        softmax_causal<<<dim3(chunk, B), blk, 0, stream>>>(S, inv_l, T, toff, chunk);
        // O = P * V  (NT vs VT, K capped at diagonal, scaled by 1/l, longest first)
        gemm_nt<<<dim3(C / BN, chunk / BM, B), blk, 0, stream>>>(
            S, T, (size_t)chunk * T,
            VT, T, (size_t)T * C,
            Ob + (size_t)toff * C, nullptr, nullptr, C, (size_t)T * C,
            chunk, C, T, 1.f,
            nullptr, inv_l, chunk, 1, 0, 0, 1, toff, 1);
    }

    // Y = O * Wo^T + bo  (fp32 out)
    gemm_nt<<<dim3(C / BN, M / BM, 1), blk, 0, stream>>>(
        Ob, C, 0, Wob, C, 0, out, nullptr, nullptr, C, 0, M, C, C, 1.f,
        bo, nullptr, 0, 0, 0, 0, 0, 0, 0);
}

// Round 6
// 626.981 us; speedup vs baseline: 1.0815x; 1.0815x over previous
//
#include <hip/hip_runtime.h>

typedef __bf16 bf16;
typedef __bf16 bf16x4 __attribute__((ext_vector_type(4)));
typedef __bf16 bf16x8 __attribute__((ext_vector_type(8)));
typedef float  f32x4  __attribute__((ext_vector_type(4)));

#define BM 128
#define BN 128
#define BK 64

__device__ __forceinline__ void async_copy16(const void* g, void* l) {
    __builtin_amdgcn_global_load_lds(
        (__attribute__((address_space(1))) void*)(g),
        (__attribute__((address_space(3))) void*)(l),
        16, 0, 0);
}

// C[z,m,n] = alpha * rs[z,m] * sum_k A[z,m,k]*B[z,n,k]  (+bias[n])
// NT GEMM, z-batched, BK=64. r0 single-buffer 2-phase core restored:
// 32 KB LDS -> 5 blocks/CU residency; latency hiding is multi-block TLP
// (m114). MEASURED on this problem: dbuf-64KB (2 blk/CU) S-GEMM 198us,
// 256^2 8-phase (1 blk/CU) 190us, THIS core 154us. Residency > pipeline.
// T1 band swizzle GATED to dense grids (r4: causal swizzle gives XCD0 the
// always-live low-n0 columns -> 12:1 live-block imbalance, S 154->169us;
// dense QKV gained). gx=8 grids (PV, proj): remap is identity.
// LDS rows are 128 B; 16B-group index XORed with row&7 both at stage and
// read time -> uniform 2-way bank access per quarter-wave (free, m136).
// qkv_mode: N spans 3 concatenated 1024-col output buffers C0/C1/C2.
// rev_m: longest-work-first block order for triangular (causal/kcap) grids.
__global__ __launch_bounds__(256)
void gemm_nt(const bf16* __restrict__ A, int lda, size_t az,
             const bf16* __restrict__ B, int ldb, size_t bz,
             void* __restrict__ C0, void* __restrict__ C1, void* __restrict__ C2,
             int ldc, size_t cz,
             int M, int N, int K, float alpha,
             const float* __restrict__ bias,
             const float* __restrict__ row_scale, int rsz,
             int out_bf16, int qkv_mode, int causal_skip, int kcap,
             int row_off, int rev_m)
{
    int z  = blockIdx.z;
    int by = rev_m ? (gridDim.y - 1 - blockIdx.y) : blockIdx.y;
    int m0 = by * BM;
    int gx = (int)gridDim.x;
    int bx = (int)blockIdx.x;
    // T1 band swizzle: dense grids only (causal balance, see header comment)
    if ((gx & 7) == 0 && !causal_skip) bx = ((bx & 7) * (gx >> 3)) + (bx >> 3);
    int n0 = bx * BN;
    if (causal_skip && n0 > row_off + m0 + BM - 1) return;  // above diagonal
    int Keff = kcap ? min(K, row_off + m0 + BM) : K;        // multiple of 128
    A += (size_t)z * az;
    B += (size_t)z * bz;

    __shared__ __attribute__((aligned(16))) bf16 As[BM * BK];  // 16 KB
    __shared__ __attribute__((aligned(16))) bf16 Bs[BN * BK];  // 16 KB

    int tid  = threadIdx.x;
    int lane = tid & 63;
    int q    = lane >> 4;    // 0..3  (k-subgroup)
    int r    = lane & 15;    // 0..15 (row-in-16)
    int wave = tid >> 6;
    int wm   = (wave >> 1) * 64;
    int wn   = (wave & 1) * 64;
    int sw   = r & 7;                                     // read-side swizzle
    int gsw  = (((tid & 7) ^ ((tid >> 3) & 7)) * 8);      // stage-side swizzle

    f32x4 acc[4][4];
#pragma unroll
    for (int i = 0; i < 4; i++)
#pragma unroll
        for (int j = 0; j < 4; j++) acc[i][j] = (f32x4){0.f, 0.f, 0.f, 0.f};

    // staging: 8 issues x 4 KB = 32 KB per k-tile. Thread tid owns LDS bytes
    // tid*16 (+4 KB per issue); fetches swizzled global k-group so LDS group
    // p of row rr holds global group p^(rr&7).
    const bf16* Ag = A + (size_t)(m0 + (tid >> 3)) * lda + gsw;
    const bf16* Bg = B + (size_t)(n0 + (tid >> 3)) * ldb + gsw;
    char* lAs = (char*)As + tid * 16;
    char* lBs = (char*)Bs + tid * 16;
    size_t astep = (size_t)32 * lda;
    size_t bstep = (size_t)32 * ldb;

    for (int k0 = 0; k0 < Keff; k0 += BK) {
#pragma unroll
        for (int i = 0; i < 4; i++) {
            async_copy16(Ag + k0 + i * astep, lAs + i * 4096);
            async_copy16(Bg + k0 + i * bstep, lBs + i * 4096);
        }
        asm volatile("s_waitcnt vmcnt(0)" ::: "memory");
        __syncthreads();

#pragma unroll
        for (int kk = 0; kk < 2; kk++) {
            bf16x8 av[4], bv[4];
#pragma unroll
            for (int mi = 0; mi < 4; mi++)
                av[mi] = *(const bf16x8*)&As[(wm + mi * 16 + r) * BK
                                            + (((kk << 2) + q) ^ sw) * 8];
#pragma unroll
            for (int ni = 0; ni < 4; ni++)
                bv[ni] = *(const bf16x8*)&Bs[(wn + ni * 16 + r) * BK
                                            + (((kk << 2) + q) ^ sw) * 8];
#pragma unroll
            for (int mi = 0; mi < 4; mi++)
#pragma unroll
                for (int ni = 0; ni < 4; ni++)
                    acc[mi][ni] = __builtin_amdgcn_mfma_f32_16x16x32_bf16(
                        av[mi], bv[ni], acc[mi][ni], 0, 0, 0);
        }
        __syncthreads();
    }

    const float* rs = row_scale ? row_scale + (size_t)z * rsz : nullptr;
    void* Cb = C0;
    if (qkv_mode) { int sel = n0 >> 10; Cb = sel == 0 ? C0 : (sel == 1 ? C1 : C2); }
    // epilogue: C/D layout col=lane&15, row=(lane>>4)*4+j  (m89-verified)
#pragma unroll
    for (int mi = 0; mi < 4; mi++) {
#pragma unroll
        for (int ni = 0; ni < 4; ni++) {
#pragma unroll
            for (int j = 0; j < 4; j++) {
                int row = m0 + wm + mi * 16 + q * 4 + j;
                int col = n0 + wn + ni * 16 + r;
                if (qkv_mode) col &= 1023;
                float v = acc[mi][ni][j] * alpha;
                if (rs)   v *= rs[row];
                if (bias) v += bias[col];
                if (out_bf16) ((bf16*)Cb + (size_t)z * cz)[(size_t)row * ldc + col] = (bf16)v;
                else          ((float*)Cb + (size_t)z * cz)[(size_t)row * ldc + col] = v;
            }
        }
    }
}

// One block per score row, bf16 scores in/out IN PLACE (row stride T bf16).
// Writes unnormalized P (zero-padded to the 128-block boundary) + 1/rowsum.
__global__ __launch_bounds__(256)
void softmax_causal(bf16* __restrict__ S, float* __restrict__ inv_l,
                    int T, int toff, int chunk)
{
    int tr = blockIdx.x, z = blockIdx.y;
    int t  = toff + tr;
    int L  = t + 1;
    int Lw = ((t >> 7) + 1) << 7;
    bf16* row = S + ((size_t)z * chunk + tr) * T;
    int tid = threadIdx.x;
    __shared__ float buf[4096];
    __shared__ float red[4];

    for (int s = tid * 8; s < Lw; s += 2048) {
        bf16x8 v = *(const bf16x8*)(row + s);
#pragma unroll
        for (int i = 0; i < 8; i++)
            buf[s + i] = (s + i < L) ? (float)v[i] : -3.0e38f;
    }
    __syncthreads();

    float m = -3.0e38f;
    for (int s = tid; s < Lw; s += 256) m = fmaxf(m, buf[s]);
#pragma unroll
    for (int off = 32; off > 0; off >>= 1) m = fmaxf(m, __shfl_down(m, off, 64));
    if ((tid & 63) == 0) red[tid >> 6] = m;
    __syncthreads();
    m = fmaxf(fmaxf(red[0], red[1]), fmaxf(red[2], red[3]));
    __syncthreads();

    float sum = 0.f;
    for (int s = tid * 8; s < Lw; s += 2048) {
        bf16x8 o;
#pragma unroll
        for (int i = 0; i < 8; i++) {
            float e = __expf(buf[s + i] - m);  // padded lanes -> 0
            sum += e;
            o[i] = (bf16)e;
        }
        *(bf16x8*)(row + s) = o;
    }
#pragma unroll
    for (int off = 32; off > 0; off >>= 1) sum += __shfl_down(sum, off, 64);
    if ((tid & 63) == 0) red[tid >> 6] = sum;
    __syncthreads();
    if (tid == 0) inv_l[(size_t)z * chunk + tr] = 1.0f / (red[0] + red[1] + red[2] + red[3]);
}

// batched transpose: V (B,T,C) -> VT (B,C,T), bf16
__global__ __launch_bounds__(256)
void transpose64(const bf16* __restrict__ V, bf16* __restrict__ VT, int T, int C)
{
    __shared__ bf16 tile[64][65];
    int b  = blockIdx.z;
    int s0 = blockIdx.x * 64, d0 = blockIdx.y * 64;
    const bf16* Vb  = V  + (size_t)b * T * C;
    bf16*       VTb = VT + (size_t)b * T * C;
    int tx = threadIdx.x & 63, ty = threadIdx.x >> 6;
#pragma unroll
    for (int i = 0; i < 64; i += 4)
        tile[ty + i][tx] = Vb[(size_t)(s0 + ty + i) * C + d0 + tx];
    __syncthreads();
#pragma unroll
    for (int i = 0; i < 64; i += 4)
        VTb[(size_t)(d0 + ty + i) * T + s0 + tx] = tile[tx][ty + i];
}

__global__ void cvt_f32_bf16(const float4* __restrict__ in, bf16x4* __restrict__ out, int n4)
{
    int i = blockIdx.x * blockDim.x + threadIdx.x;
    int stride = gridDim.x * blockDim.x;
    for (; i < n4; i += stride) {
        float4 v = in[i];
        bf16x4 o = { (bf16)v.x, (bf16)v.y, (bf16)v.z, (bf16)v.w };
        out[i] = o;
    }
}

extern "C" void kernel_launch(void* const* d_in, const int* in_sizes, int n_in,
                              void* d_out, int out_size, void* d_ws, size_t ws_size,
                              hipStream_t stream)
{
    const int B = 4, T = 4096, C = 1024, M = B * T;
    const float* x  = (const float*)d_in[0];
    const float* Wq = (const float*)d_in[1];
    const float* Wk = (const float*)d_in[2];
    const float* Wv = (const float*)d_in[3];
    const float* Wo = (const float*)d_in[4];
    const float* bo = (const float*)d_in[5];
    float* out = (float*)d_out;

    char* ws = (char*)d_ws;
    size_t off = 0;
    auto alloc = [&](size_t bytes) -> char* {
        char* p = ws + off;
        off += (bytes + 255) & ~(size_t)255;
        return p;
    };
    bf16* Wcat = (bf16*)alloc((size_t)3 * C * C * 2);  // [Wq; Wk; Wv]
    bf16* Wob  = (bf16*)alloc((size_t)C * C * 2);
    bf16* Qb   = (bf16*)alloc((size_t)M * C * 2);
    bf16* Kb   = (bf16*)alloc((size_t)M * C * 2);
    bf16* VT   = (bf16*)alloc((size_t)M * C * 2);

    // Preferred plan (chunk = T, ~232 MB — ws proven >= 235 MB in round 1):
    //   S region hosts xb and raw-V during projection (dead before S written);
    //   attention output O aliases Qb (Q dead after the single S-GEMM).
    size_t base = off;
    int chunk = T;
    bf16 *S, *xb, *Vtmp, *Ob;
    float* inv_l;
    {
        size_t need = base + (((size_t)B * T * T * 2 + 255) & ~(size_t)255)
                           + (((size_t)B * T * 4 + 255) & ~(size_t)255);
        if (need <= ws_size) {
            S     = (bf16*)alloc((size_t)B * T * T * 2);
            inv_l = (float*)alloc((size_t)B * T * 4);
            xb    = S;
            Vtmp  = S + (size_t)M * C;   // 32 MB past xb, inside S region
            Ob    = Qb;                  // O overwrites Q after S-GEMM
        } else {
            Ob = (bf16*)alloc((size_t)M * C * 2);
            chunk = T / 2;
            while (chunk > 1024) {
                size_t nd = off + (((size_t)B * chunk * T * 2 + 255) & ~(size_t)255)
                                + (((size_t)B * chunk * 4 + 255) & ~(size_t)255);
                if (nd <= ws_size) break;
                chunk >>= 1;
            }
            S     = (bf16*)alloc((size_t)B * chunk * T * 2);
            inv_l = (float*)alloc((size_t)B * chunk * 4);
            xb    = S;   // x dead after QKV projection
            Vtmp  = Ob;  // V staged in Ob, transposed before PV writes Ob
        }
    }

    dim3 blk(256);

    cvt_f32_bf16<<<dim3(4096), blk, 0, stream>>>((const float4*)x,  (bf16x4*)xb, M * C / 4);
    cvt_f32_bf16<<<dim3(1024), blk, 0, stream>>>((const float4*)Wq, (bf16x4*)(Wcat),             C * C / 4);
    cvt_f32_bf16<<<dim3(1024), blk, 0, stream>>>((const float4*)Wk, (bf16x4*)(Wcat + C * C),     C * C / 4);
    cvt_f32_bf16<<<dim3(1024), blk, 0, stream>>>((const float4*)Wv, (bf16x4*)(Wcat + 2 * C * C), C * C / 4);
    cvt_f32_bf16<<<dim3(1024), blk, 0, stream>>>((const float4*)Wo, (bf16x4*)Wob, C * C / 4);

    // fused QKV projection: [Q|K|V] = X * Wcat^T
    gemm_nt<<<dim3(3 * C / BN, M / BM, 1), blk, 0, stream>>>(
        xb, C, 0, Wcat, C, 0, Qb, Kb, Vtmp, C, 0, M, 3 * C, C, 1.f,
        nullptr, nullptr, 0, 1, 1, 0, 0, 0, 0);
    transpose64<<<dim3(T / 64, C / 64, B), blk, 0, stream>>>(Vtmp, VT, T, C);

    const float scale = 0.03125f;  // 1/sqrt(1024)
    for (int toff = 0; toff < T; toff += chunk) {
        // S = Q_chunk * K^T * scale  (bf16 out, causal skip, longest-m first)
        gemm_nt<<<dim3(T / BN, chunk / BM, B), blk, 0, stream>>>(
            Qb + (size_t)toff * C, C, (size_t)T * C,
            Kb, C, (size_t)T * C,
            S, nullptr, nullptr, T, (size_t)chunk * T,
            chunk, T, C, scale,
            nullptr, nullptr, 0, 1, 0, 1, 0, toff, 1);
        // causal softmax in place -> unnormalized bf16 P + 1/rowsum
        softmax_causal<<<dim3(chunk, B), blk, 0, stream>>>(S, inv_l, T, toff, chunk);
        // O = P * V  (NT vs VT, K capped at diagonal, scaled by 1/l, longest first)
        gemm_nt<<<dim3(C / BN, chunk / BM, B), blk, 0, stream>>>(
            S, T, (size_t)chunk * T,
            VT, T, (size_t)T * C,
            Ob + (size_t)toff * C, nullptr, nullptr, C, (size_t)T * C,
            chunk, C, T, 1.f,
            nullptr, inv_l, chunk, 1, 0, 0, 1, toff, 1);
    }

    // Y = O * Wo^T + bo  (fp32 out)
    gemm_nt<<<dim3(C / BN, M / BM, 1), blk, 0, stream>>>(
        Ob, C, 0, Wob, C, 0, out, nullptr, nullptr, C, 0, M, C, C, 1.f,
        bo, nullptr, 0, 0, 0, 0, 0, 0, 0);
}